// Round 13
// baseline (143.481 us; speedup 1.0000x reference)
//
#include <hip/hip_runtime.h>
#include <math.h>

#define NN 3072
#define NH 8
#define FO 64
#define FCAT 512
#define MAXDEG 128
#define PBPAD 136
#define ALPHA 0.2f

typedef __attribute__((ext_vector_type(8))) short bf16x8;
typedef __attribute__((ext_vector_type(4))) float f32x4;

static __device__ __forceinline__ unsigned short f2bf(float v) {
    union { float f; unsigned u; } x; x.f = v;
    unsigned r = x.u + 0x7fffu + ((x.u >> 16) & 1u);
    return (unsigned short)(r >> 16);
}
static __device__ __forceinline__ float bf2f(unsigned short b) {
    union { unsigned u; float f; } x; x.u = ((unsigned)b) << 16;
    return x.f;
}

// ---------------- fused prelude: conv_x + conv_wt + csr ----------------
__global__ __launch_bounds__(256) void prelude_k(const float* __restrict__ x,
                                                 const float* __restrict__ adj,
                                                 const float* __restrict__ W1,
                                                 const float* __restrict__ W2,
                                                 const float* __restrict__ W3,
                                                 const float* __restrict__ W4,
                                                 unsigned short* __restrict__ Ah,
                                                 unsigned short* __restrict__ Al,
                                                 unsigned short* __restrict__ Wth,
                                                 unsigned short* __restrict__ Wtl,
                                                 int* __restrict__ deg,
                                                 int* __restrict__ nbr) {
    __shared__ float t[64][65];
    const int b = blockIdx.x, tid = threadIdx.x;

    if (b < 256) {
        int base = b * 1536 + tid;
        #pragma unroll
        for (int i = 0; i < 6; ++i) {
            int idx = base + i * 256;
            float v = x[idx];
            unsigned short hb = f2bf(v);
            Ah[idx] = hb;
            Al[idx] = f2bf(v - bf2f(hb));
        }
        if (b < 208) {
            const float* W; int K; int local; size_t obase;
            if (b < 16)       { W = W1; K = 128; local = b;       obase = 0; }
            else if (b < 80)  { W = W2; K = 512; local = b - 16;  obase = 65536; }
            else if (b < 144) { W = W3; K = 512; local = b - 80;  obase = 327680; }
            else              { W = W4; K = 512; local = b - 144; obase = 589824; }
            int nkt = K >> 6;
            int h = local / nkt, kt = local - h * nkt;
            int k0 = kt * 64;
            for (int idx = tid; idx < 4096; idx += 256) {
                int r = idx >> 6, c = idx & 63;
                t[r][c] = W[(size_t)h * K * FO + (size_t)(k0 + r) * FO + c];
            }
            __syncthreads();
            for (int idx = tid; idx < 4096; idx += 256) {
                int o = idx >> 6, kk = idx & 63;
                float v = t[kk][o];
                unsigned short hb = f2bf(v);
                size_t dst = obase + (size_t)(h * FO + o) * K + k0 + kk;
                Wth[dst] = hb;
                Wtl[dst] = f2bf(v - bf2f(hb));
            }
        }
    } else {
        int row = (b - 256) * 4 + (tid >> 6);
        int lane = tid & 63;
        const float* arow = adj + (size_t)row * NN;
        int count = 0;
        for (int base = 0; base < NN; base += 64) {
            float v = arow[base + lane];
            unsigned long long m = __ballot(v > 0.0f);
            if (v > 0.0f) {
                int pos = count + __popcll(m & ((1ull << lane) - 1ull));
                if (pos < MAXDEG) nbr[(size_t)row * MAXDEG + pos] = base + lane;
            }
            count += __popcll(m);
        }
        if (lane == 0) deg[row] = count < MAXDEG ? count : MAXDEG;
    }
}

// ---------------- split-bf16 MFMA GEMM: 32x64 tile, VGPR prefetch, 3 blocks/CU --------------
// grid (NH, NN/32); block 256 = 4 waves (2 wr x 2 wc). ee epilogue -> ee[n][16] layout.
__global__ __launch_bounds__(256, 3) void gemm_ee_k(const unsigned short* __restrict__ Ah,
                                                    const unsigned short* __restrict__ Al,
                                                    const unsigned short* __restrict__ Bh,
                                                    const unsigned short* __restrict__ Bl,
                                                    const float* __restrict__ a,
                                                    float* __restrict__ C,
                                                    float* __restrict__ ee, int K) {
    __shared__ __align__(16) unsigned char smem[30720];
    typedef float CsT[68];
    unsigned short* As_ = (unsigned short*)smem;            // As[2][32][80] hi/lo (10240 B)
    unsigned short* Bs_ = (unsigned short*)(smem + 10240);  // Bs[2][64][80] (20480 B)
    CsT* Cs = reinterpret_cast<CsT*>(smem);                 // Cs[32][68] overlay (8704 B)

    const int tid = threadIdx.x;
    const int h = blockIdx.x;
    const int r0 = blockIdx.y * 32;
    const int lane = tid & 63;
    const int wid = tid >> 6;
    const int wr = wid >> 1, wc = wid & 1;
    const int lr = lane & 15, lg = lane >> 4;

    const unsigned short* Bhh = Bh + (size_t)h * FO * K;
    const unsigned short* Bll = Bl + (size_t)h * FO * K;

    const int row0 = tid >> 3, cq0 = tid & 7;
    const int off0 = row0 * 80 + ((cq0 ^ (row0 & 7)) * 8);
    const size_t gA0 = (size_t)(r0 + row0) * K + cq0 * 8;
    const size_t gB0 = (size_t)row0 * K + cq0 * 8;
    const size_t gB1 = gB0 + (size_t)32 * K;

    bf16x8 rah, ral, rb0h, rb0l, rb1h, rb1l;

    auto loadg = [&](int k0) {
        rah = *(const bf16x8*)(Ah + gA0 + k0);
        ral = *(const bf16x8*)(Al + gA0 + k0);
        rb0h = *(const bf16x8*)(Bhh + gB0 + k0);
        rb0l = *(const bf16x8*)(Bll + gB0 + k0);
        rb1h = *(const bf16x8*)(Bhh + gB1 + k0);
        rb1l = *(const bf16x8*)(Bll + gB1 + k0);
    };
    auto store_lds = [&]() {
        *(bf16x8*)&As_[off0] = rah;
        *(bf16x8*)&As_[2560 + off0] = ral;
        *(bf16x8*)&Bs_[off0] = rb0h;
        *(bf16x8*)&Bs_[5120 + off0] = rb0l;
        *(bf16x8*)&Bs_[off0 + 2560] = rb1h;
        *(bf16x8*)&Bs_[5120 + off0 + 2560] = rb1l;
    };

    f32x4 acc[2];
    acc[0] = (f32x4){0.f, 0.f, 0.f, 0.f};
    acc[1] = (f32x4){0.f, 0.f, 0.f, 0.f};

    auto mfma_phase = [&]() {
        #pragma unroll
        for (int ks = 0; ks < 2; ++ks) {
            int cq = ks * 4 + lg;
            int arow = wr * 16 + lr;
            int offa = arow * 80 + ((cq ^ (arow & 7)) * 8);
            bf16x8 ah = *(const bf16x8*)&As_[offa];
            bf16x8 al = *(const bf16x8*)&As_[2560 + offa];
            bf16x8 bh[2], bl[2];
            #pragma unroll
            for (int j = 0; j < 2; ++j) {
                int col = wc * 32 + j * 16 + lr;
                int offb = col * 80 + ((cq ^ (col & 7)) * 8);
                bh[j] = *(const bf16x8*)&Bs_[offb];
                bl[j] = *(const bf16x8*)&Bs_[5120 + offb];
            }
            #pragma unroll
            for (int j = 0; j < 2; ++j) {
                acc[j] = __builtin_amdgcn_mfma_f32_16x16x32_bf16(ah, bh[j], acc[j], 0, 0, 0);
                acc[j] = __builtin_amdgcn_mfma_f32_16x16x32_bf16(ah, bl[j], acc[j], 0, 0, 0);
                acc[j] = __builtin_amdgcn_mfma_f32_16x16x32_bf16(al, bh[j], acc[j], 0, 0, 0);
            }
        }
    };

    loadg(0);
    store_lds();
    __syncthreads();
    for (int k0 = 64; k0 < K; k0 += 64) {
        loadg(k0);
        mfma_phase();
        __syncthreads();
        store_lds();
        __syncthreads();
    }
    mfma_phase();
    __syncthreads();

    #pragma unroll
    for (int j = 0; j < 2; ++j)
        #pragma unroll
        for (int r = 0; r < 4; ++r)
            Cs[wr * 16 + lg * 4 + r][wc * 32 + j * 16 + lr] = acc[j][r];
    __syncthreads();

    #pragma unroll
    for (int it = 0; it < 2; ++it) {
        int idx = tid + it * 256;
        int r = idx >> 4, c4 = idx & 15;
        *(float4*)&C[(size_t)(r0 + r) * FCAT + h * FO + c4 * 4] = *(float4*)&Cs[r][c4 * 4];
    }

    // fused e_src/e_dst -> ee[n][16]: [0..8)=esrc, [8..16)=edst
    {
        int r = tid >> 3, sub = tid & 7;
        const float* av = a + h * 2 * FO;
        float s = 0.0f, dd = 0.0f;
        #pragma unroll
        for (int k = 0; k < 8; ++k) {
            float v = Cs[r][sub * 8 + k];
            s = fmaf(v, av[sub * 8 + k], s);
            dd = fmaf(v, av[FO + sub * 8 + k], dd);
        }
        s += __shfl_xor(s, 1); s += __shfl_xor(s, 2); s += __shfl_xor(s, 4);
        dd += __shfl_xor(dd, 1); dd += __shfl_xor(dd, 2); dd += __shfl_xor(dd, 4);
        if (sub == 0) {
            ee[(size_t)(r0 + r) * 16 + h] = s;
            ee[(size_t)(r0 + r) * 16 + 8 + h] = dd;
        }
    }
}

// ---------------- attention + aggregation: one wave per (node, 4-head group) ----------------
// grid = 2 * NN/4 blocks, hgroup-major; lane loads float4 spanning 4 heads' slices.
__global__ __launch_bounds__(256) void attn_agg_k(const float* __restrict__ Wh,
                                                  const float* __restrict__ ee,
                                                  const int* __restrict__ deg,
                                                  const int* __restrict__ nbr,
                                                  float* __restrict__ outp,
                                                  unsigned short* __restrict__ oh,
                                                  unsigned short* __restrict__ ol,
                                                  int write_f32) {
    __shared__ float pbuf[4][4][PBPAD];   // [wave][head-in-group][t], padded vs bank alias
    __shared__ int jbuf[4][MAXDEG];
    const int ws = threadIdx.x >> 6;
    const int lane = threadIdx.x & 63;
    const int hg = blockIdx.x / (NN / 4);            // 0 or 1
    const int n = (blockIdx.x % (NN / 4)) * 4 + ws;
    const int h0 = hg * 4;
    const int d = deg[n];
    const int* nb = nbr + (size_t)n * MAXDEG;
    float (*pb)[PBPAD] = pbuf[ws];

    // e-phase: one float4 edst read per neighbor covers 4 heads
    const float es0 = ee[(size_t)n * 16 + h0];
    const float es1 = ee[(size_t)n * 16 + h0 + 1];
    const float es2 = ee[(size_t)n * 16 + h0 + 2];
    const float es3 = ee[(size_t)n * 16 + h0 + 3];
    for (int t = lane; t < d; t += 64) {
        int j = nb[t];
        jbuf[ws][t] = j;
        float4 ed4 = *(const float4*)&ee[(size_t)j * 16 + 8 + h0];
        float e0 = es0 + ed4.x; e0 = (e0 > 0.0f) ? e0 : ALPHA * e0;
        float e1 = es1 + ed4.y; e1 = (e1 > 0.0f) ? e1 : ALPHA * e1;
        float e2 = es2 + ed4.z; e2 = (e2 > 0.0f) ? e2 : ALPHA * e2;
        float e3 = es3 + ed4.w; e3 = (e3 > 0.0f) ? e3 : ALPHA * e3;
        pb[0][t] = e0; pb[1][t] = e1; pb[2][t] = e2; pb[3][t] = e3;
    }

    // softmax per head (full-wave cooperative, bit-identical reduce order)
    float lsum[4];
    #pragma unroll
    for (int hh = 0; hh < 4; ++hh) {
        float lm = -3.0e38f;
        for (int t = lane; t < d; t += 64) lm = fmaxf(lm, pb[hh][t]);
        #pragma unroll
        for (int off = 32; off; off >>= 1) lm = fmaxf(lm, __shfl_xor(lm, off));
        float s = 0.0f;
        for (int t = lane; t < d; t += 64) {
            float pv = __expf(pb[hh][t] - lm);
            pb[hh][t] = pv;
            s += pv;
        }
        #pragma unroll
        for (int off = 32; off; off >>= 1) s += __shfl_xor(s, off);
        lsum[hh] = s;
    }

    // gather: lane's float4 = head (h0 + lane/16), cols (lane%16)*4..+3
    const int lg = lane >> 4;
    const float* whb = Wh + hg * 256 + lane * 4;
    float4 a0 = {0.f,0.f,0.f,0.f}, a1 = a0, a2 = a0, a3 = a0;
    int t = 0;
    for (; t + 3 < d; t += 4) {
        int j0 = jbuf[ws][t], j1 = jbuf[ws][t+1], j2 = jbuf[ws][t+2], j3 = jbuf[ws][t+3];
        float p0 = pb[lg][t], p1 = pb[lg][t+1], p2 = pb[lg][t+2], p3 = pb[lg][t+3];
        float4 v0 = *(const float4*)&whb[(size_t)j0 * FCAT];
        float4 v1 = *(const float4*)&whb[(size_t)j1 * FCAT];
        float4 v2 = *(const float4*)&whb[(size_t)j2 * FCAT];
        float4 v3 = *(const float4*)&whb[(size_t)j3 * FCAT];
        a0.x = fmaf(p0, v0.x, a0.x); a0.y = fmaf(p0, v0.y, a0.y);
        a0.z = fmaf(p0, v0.z, a0.z); a0.w = fmaf(p0, v0.w, a0.w);
        a1.x = fmaf(p1, v1.x, a1.x); a1.y = fmaf(p1, v1.y, a1.y);
        a1.z = fmaf(p1, v1.z, a1.z); a1.w = fmaf(p1, v1.w, a1.w);
        a2.x = fmaf(p2, v2.x, a2.x); a2.y = fmaf(p2, v2.y, a2.y);
        a2.z = fmaf(p2, v2.z, a2.z); a2.w = fmaf(p2, v2.w, a2.w);
        a3.x = fmaf(p3, v3.x, a3.x); a3.y = fmaf(p3, v3.y, a3.y);
        a3.z = fmaf(p3, v3.z, a3.z); a3.w = fmaf(p3, v3.w, a3.w);
    }
    for (; t < d; ++t) {
        float p = pb[lg][t];
        float4 v = *(const float4*)&whb[(size_t)jbuf[ws][t] * FCAT];
        a0.x = fmaf(p, v.x, a0.x); a0.y = fmaf(p, v.y, a0.y);
        a0.z = fmaf(p, v.z, a0.z); a0.w = fmaf(p, v.w, a0.w);
    }
    float4 acc;
    acc.x = (a0.x + a1.x) + (a2.x + a3.x);
    acc.y = (a0.y + a1.y) + (a2.y + a3.y);
    acc.z = (a0.z + a1.z) + (a2.z + a3.z);
    acc.w = (a0.w + a1.w) + (a2.w + a3.w);
    float ls = (lg == 0) ? lsum[0] : (lg == 1) ? lsum[1] : (lg == 2) ? lsum[2] : lsum[3];
    float inv = 1.0f / ls;
    acc.x *= inv; acc.y *= inv; acc.z *= inv; acc.w *= inv;
    acc.x = (acc.x > 0.0f) ? acc.x : (__expf(acc.x) - 1.0f);
    acc.y = (acc.y > 0.0f) ? acc.y : (__expf(acc.y) - 1.0f);
    acc.z = (acc.z > 0.0f) ? acc.z : (__expf(acc.z) - 1.0f);
    acc.w = (acc.w > 0.0f) ? acc.w : (__expf(acc.w) - 1.0f);

    size_t idx = (size_t)n * FCAT + hg * 256 + lane * 4;
    if (write_f32) {
        *(float4*)&outp[idx] = acc;
    } else {
        unsigned short h0b = f2bf(acc.x), h1b = f2bf(acc.y), h2b = f2bf(acc.z), h3b = f2bf(acc.w);
        ushort4 hv = {h0b, h1b, h2b, h3b};
        ushort4 lv = {f2bf(acc.x - bf2f(h0b)), f2bf(acc.y - bf2f(h1b)),
                      f2bf(acc.z - bf2f(h2b)), f2bf(acc.w - bf2f(h3b))};
        *(ushort4*)&oh[idx] = hv;
        *(ushort4*)&ol[idx] = lv;
    }
}

extern "C" void kernel_launch(void* const* d_in, const int* in_sizes, int n_in,
                              void* d_out, int out_size, void* d_ws, size_t ws_size,
                              hipStream_t stream) {
    const float* x   = (const float*)d_in[0];
    const float* adj = (const float*)d_in[1];
    const float* ap[4] = {(const float*)d_in[3], (const float*)d_in[5],
                          (const float*)d_in[7], (const float*)d_in[9]};
    float* out = (float*)d_out;

    char* p = (char*)d_ws;
    int* deg = (int*)p;              p += (size_t)NN * sizeof(int);
    int* nbr = (int*)p;              p += (size_t)NN * MAXDEG * sizeof(int);
    unsigned short* Ah = (unsigned short*)p; p += (size_t)NN * FCAT * 2;
    unsigned short* Al = (unsigned short*)p; p += (size_t)NN * FCAT * 2;
    float* WhF = (float*)p;          p += (size_t)NN * FCAT * sizeof(float);
    unsigned short* Wth = (unsigned short*)p; p += (size_t)851968 * 2;
    unsigned short* Wtl = (unsigned short*)p; p += (size_t)851968 * 2;
    float* ee = (float*)p;           p += (size_t)NN * 16 * sizeof(float);

    prelude_k<<<1024, 256, 0, stream>>>(x, adj,
                                        (const float*)d_in[2], (const float*)d_in[4],
                                        (const float*)d_in[6], (const float*)d_in[8],
                                        Ah, Al, Wth, Wtl, deg, nbr);

    const size_t woff[4] = {0, 65536, 327680, 589824};
    int K = 128;
    for (int L = 0; L < 4; ++L) {
        dim3 g(NH, NN / 32);
        gemm_ee_k<<<g, 256, 0, stream>>>(Ah, Al, Wth + woff[L], Wtl + woff[L],
                                         ap[L], WhF, ee, K);
        attn_agg_k<<<2 * (NN / 4), 256, 0, stream>>>(WhF, ee, deg, nbr,
                                                     out, Ah, Al, L == 3 ? 1 : 0);
        K = FCAT;
    }
}